// Round 1
// baseline (617.250 us; speedup 1.0000x reference)
//
#include <hip/hip_runtime.h>
#include <math.h>

// ---------------------------------------------------------------------------
// CSR build: histogram -> single-block scan -> scatter
// ---------------------------------------------------------------------------
__global__ void k_hist(const int* __restrict__ keys, int n, int* __restrict__ deg) {
    int i = blockIdx.x * blockDim.x + threadIdx.x;
    if (i < n) atomicAdd(&deg[keys[i]], 1);
}

// exclusive scan of deg[0..n) -> ptr[0..n] and cursor[0..n); single block, 1024 thr
__global__ void k_scan(const int* __restrict__ deg, int n,
                       int* __restrict__ ptr, int* __restrict__ cur) {
    __shared__ int part[1024];
    const int t = threadIdx.x;
    const int chunk = (n + 1023) / 1024;
    int b = t * chunk;
    int e = b + chunk; if (e > n) e = n;
    int s = 0;
    for (int i = b; i < e; i++) s += deg[i];
    part[t] = s;
    __syncthreads();
    // Hillis-Steele inclusive scan
    for (int off = 1; off < 1024; off <<= 1) {
        int v = part[t];
        int u = (t >= off) ? part[t - off] : 0;
        __syncthreads();
        part[t] = v + u;
        __syncthreads();
    }
    int excl = (t == 0) ? 0 : part[t - 1];
    for (int i = b; i < e; i++) {
        ptr[i] = excl; cur[i] = excl;
        excl += deg[i];
    }
    if (t == 1023) ptr[n] = part[1023];
}

__global__ void k_scatter_edges(const int* __restrict__ dst, const int* __restrict__ src,
                                int E, int* __restrict__ cur, int* __restrict__ colidx) {
    int e = blockIdx.x * blockDim.x + threadIdx.x;
    if (e < E) {
        int d = dst[e];
        int pos = atomicAdd(&cur[d], 1);
        colidx[pos] = src[e];
    }
}

__global__ void k_scatter_nodes(const int* __restrict__ key, int N,
                                int* __restrict__ cur, int* __restrict__ idx) {
    int i = blockIdx.x * blockDim.x + threadIdx.x;
    if (i < N) {
        int c = key[i];
        int pos = atomicAdd(&cur[c], 1);
        idx[pos] = i;
    }
}

// ---------------------------------------------------------------------------
// GEMM 1: t = relu(x @ w1 + b1)   x:[M,K] (dense, stride K), w1:[K,64], t:[M,64]
// 64x64 tile, 256 threads, 4x4 register blocking
// ---------------------------------------------------------------------------
template <int K>
__global__ __launch_bounds__(256) void k_mlp1(const float* __restrict__ x,
                                              const float* __restrict__ w1,
                                              const float* __restrict__ b1,
                                              float* __restrict__ t, int M) {
    __shared__ float xs[64][68];  // [k_local][row]  (transposed x tile)
    __shared__ float ws[64][68];  // [k_local][col]
    const int tid = threadIdx.x;
    const int m0 = blockIdx.x * 64;
    const int rl = tid >> 4;          // 0..15
    const int c4 = (tid & 15) * 4;    // 0,4,...,60
    float acc[4][4] = {};

    for (int k0 = 0; k0 < K; k0 += 64) {
        __syncthreads();
#pragma unroll
        for (int i = 0; i < 4; i++) {
            int r = rl + 16 * i;
            int gm = m0 + r;
            float4 v = make_float4(0.f, 0.f, 0.f, 0.f);
            if (gm < M) v = *(const float4*)&x[(size_t)gm * K + k0 + c4];
            xs[c4 + 0][r] = v.x; xs[c4 + 1][r] = v.y;
            xs[c4 + 2][r] = v.z; xs[c4 + 3][r] = v.w;
            float4 w = *(const float4*)&w1[(size_t)(k0 + r) * 64 + c4];
            *(float4*)&ws[r][c4] = w;
        }
        __syncthreads();
#pragma unroll 16
        for (int kk = 0; kk < 64; kk++) {
            float4 a = *(const float4*)&xs[kk][rl * 4];
            float4 b = *(const float4*)&ws[kk][c4];
            float ar[4] = {a.x, a.y, a.z, a.w};
            float bc[4] = {b.x, b.y, b.z, b.w};
#pragma unroll
            for (int r = 0; r < 4; r++)
#pragma unroll
                for (int c = 0; c < 4; c++)
                    acc[r][c] = fmaf(ar[r], bc[c], acc[r][c]);
        }
    }
    float4 bb = *(const float4*)&b1[c4];
    float bias[4] = {bb.x, bb.y, bb.z, bb.w};
#pragma unroll
    for (int r = 0; r < 4; r++) {
        int gm = m0 + rl * 4 + r;
        if (gm < M) {
            float4 o;
            o.x = fmaxf(acc[r][0] + bias[0], 0.f);
            o.y = fmaxf(acc[r][1] + bias[1], 0.f);
            o.z = fmaxf(acc[r][2] + bias[2], 0.f);
            o.w = fmaxf(acc[r][3] + bias[3], 0.f);
            *(float4*)&t[(size_t)gm * 64 + c4] = o;
        }
    }
}

// ---------------------------------------------------------------------------
// GEMM 2: h = t @ w2 + b2   t:[M,64], w2:[64,Nc], write h to out[m*OS + n]
// ---------------------------------------------------------------------------
__global__ __launch_bounds__(256) void k_mlp2(const float* __restrict__ t,
                                              const float* __restrict__ w2,
                                              const float* __restrict__ b2,
                                              float* __restrict__ out,
                                              int M, int Nc, int OS) {
    __shared__ float ts[64][68];
    __shared__ float ws[64][68];
    const int tid = threadIdx.x;
    const int m0 = blockIdx.x * 64;
    const int n0 = blockIdx.y * 64;
    const int rl = tid >> 4;
    const int c4 = (tid & 15) * 4;
    float acc[4][4] = {};

#pragma unroll
    for (int i = 0; i < 4; i++) {
        int r = rl + 16 * i;
        int gm = m0 + r;
        float4 v = make_float4(0.f, 0.f, 0.f, 0.f);
        if (gm < M) v = *(const float4*)&t[(size_t)gm * 64 + c4];
        ts[c4 + 0][r] = v.x; ts[c4 + 1][r] = v.y;
        ts[c4 + 2][r] = v.z; ts[c4 + 3][r] = v.w;
        float4 w = *(const float4*)&w2[(size_t)r * Nc + n0 + c4];
        *(float4*)&ws[r][c4] = w;
    }
    __syncthreads();
#pragma unroll 16
    for (int kk = 0; kk < 64; kk++) {
        float4 a = *(const float4*)&ts[kk][rl * 4];
        float4 b = *(const float4*)&ws[kk][c4];
        float ar[4] = {a.x, a.y, a.z, a.w};
        float bc[4] = {b.x, b.y, b.z, b.w};
#pragma unroll
        for (int r = 0; r < 4; r++)
#pragma unroll
            for (int c = 0; c < 4; c++)
                acc[r][c] = fmaf(ar[r], bc[c], acc[r][c]);
    }
    float4 bb = *(const float4*)&b2[n0 + c4];
    float bias[4] = {bb.x, bb.y, bb.z, bb.w};
#pragma unroll
    for (int r = 0; r < 4; r++) {
        int gm = m0 + rl * 4 + r;
        if (gm < M) {
            float4 o;
            o.x = acc[r][0] + bias[0];
            o.y = acc[r][1] + bias[1];
            o.z = acc[r][2] + bias[2];
            o.w = acc[r][3] + bias[3];
            *(float4*)&out[(size_t)gm * OS + n0 + c4] = o;
        }
    }
}

// ---------------------------------------------------------------------------
// Aggregation: per-node max over incoming edges (CSR), wave per node.
// h rows have `stride` floats; channels 0..64*R-1; aggr written at same stride.
// ---------------------------------------------------------------------------
template <int R>
__global__ void k_agg(const float* __restrict__ h, float* __restrict__ aggr,
                      const int* __restrict__ rowptr, const int* __restrict__ colidx,
                      int N, int stride) {
    int wid = (blockIdx.x * blockDim.x + threadIdx.x) >> 6;
    int lane = threadIdx.x & 63;
    if (wid >= N) return;
    int beg = rowptr[wid], end = rowptr[wid + 1];
    int ch = lane * R;
    float acc[R];
#pragma unroll
    for (int r = 0; r < R; r++) acc[r] = -INFINITY;

#pragma unroll 2
    for (int i = beg; i < end; i++) {
        int s = colidx[i];
        const float* p = h + (size_t)s * stride + ch;
        if (R == 4) {
            float4 v = *(const float4*)p;
            acc[0] = fmaxf(acc[0], v.x); acc[1] = fmaxf(acc[1], v.y);
            acc[2] = fmaxf(acc[2], v.z); acc[3] = fmaxf(acc[3], v.w);
        } else if (R == 2) {
            float2 v = *(const float2*)p;
            acc[0] = fmaxf(acc[0], v.x); acc[1] = fmaxf(acc[1], v.y);
        } else {
            acc[0] = fmaxf(acc[0], p[0]);
        }
    }
    float* q = aggr + (size_t)wid * stride + ch;
    if (beg == end) {
#pragma unroll
        for (int r = 0; r < R; r++) acc[r] = 0.f;
    }
#pragma unroll
    for (int r = 0; r < R; r++) q[r] = acc[r];
}

// ---------------------------------------------------------------------------
// Cluster max-pool: block per cluster, 256 threads x float2 (512 channels)
// ---------------------------------------------------------------------------
__global__ void k_pool(const float* __restrict__ x3, const int* __restrict__ cptr,
                       const int* __restrict__ cidx, float* __restrict__ pooled) {
    int cl = blockIdx.x;
    int tid = threadIdx.x;
    int beg = cptr[cl], end = cptr[cl + 1];
    float ax = -INFINITY, ay = -INFINITY;
    for (int i = beg; i < end; i++) {
        int n = cidx[i];
        float2 v = *(const float2*)&x3[(size_t)n * 512 + tid * 2];
        ax = fmaxf(ax, v.x); ay = fmaxf(ay, v.y);
    }
    if (beg == end) { ax = 0.f; ay = 0.f; }
    float2 o; o.x = ax; o.y = ay;
    *(float2*)&pooled[(size_t)cl * 512 + tid * 2] = o;
}

// ---------------------------------------------------------------------------
// Column-wise sum of squares (axis 0) then scale
// ---------------------------------------------------------------------------
__global__ void k_sumsq(const float* __restrict__ pooled, float* __restrict__ sumsq, int NC) {
    int tid = threadIdx.x;  // 256 threads, 2 cols each
    float ax = 0.f, ay = 0.f;
    for (int r = blockIdx.x; r < NC; r += gridDim.x) {
        float2 v = *(const float2*)&pooled[(size_t)r * 512 + tid * 2];
        ax += v.x * v.x; ay += v.y * v.y;
    }
    atomicAdd(&sumsq[tid * 2 + 0], ax);
    atomicAdd(&sumsq[tid * 2 + 1], ay);
}

__global__ void k_scale(const float* __restrict__ pooled, const float* __restrict__ sumsq,
                        float* __restrict__ out, int total) {
    int i = blockIdx.x * blockDim.x + threadIdx.x;
    int base = i * 4;
    if (base < total) {
        float4 v = *(const float4*)&pooled[base];
        int col = base & 511;
        v.x /= (sqrtf(sumsq[col + 0]) + 1e-6f);
        v.y /= (sqrtf(sumsq[col + 1]) + 1e-6f);
        v.z /= (sqrtf(sumsq[col + 2]) + 1e-6f);
        v.w /= (sqrtf(sumsq[col + 3]) + 1e-6f);
        *(float4*)&out[base] = v;
    }
}

// ---------------------------------------------------------------------------
extern "C" void kernel_launch(void* const* d_in, const int* in_sizes, int n_in,
                              void* d_out, int out_size, void* d_ws, size_t ws_size,
                              hipStream_t stream) {
    const float* x0      = (const float*)d_in[0];
    const int*   ei      = (const int*)d_in[1];
    const int*   cluster = (const int*)d_in[2];
    const float* w1_[3] = {(const float*)d_in[3], (const float*)d_in[7],  (const float*)d_in[11]};
    const float* b1_[3] = {(const float*)d_in[4], (const float*)d_in[8],  (const float*)d_in[12]};
    const float* w2_[3] = {(const float*)d_in[5], (const float*)d_in[9],  (const float*)d_in[13]};
    const float* b2_[3] = {(const float*)d_in[6], (const float*)d_in[10], (const float*)d_in[14]};

    const int N  = in_sizes[2];       // 50000
    const int E  = in_sizes[1] / 2;   // 800000
    const int NC = 2500;
    float* out = (float*)d_out;

    // workspace bump allocator
    char* p = (char*)d_ws;
    auto alloc = [&](size_t bytes) -> char* {
        char* r = p;
        p += (bytes + 255) & ~(size_t)255;
        return r;
    };
    float* x1     = (float*)alloc((size_t)N * 128 * 4);
    float* x2     = (float*)alloc((size_t)N * 256 * 4);
    float* x3     = (float*)alloc((size_t)N * 512 * 4);
    float* tbuf   = (float*)alloc((size_t)N * 64 * 4);
    float* pooled = (float*)alloc((size_t)NC * 512 * 4);
    float* sumsq  = (float*)alloc(512 * 4);
    int*   deg    = (int*)alloc((size_t)(N + 1) * 4);
    int*   rowptr = (int*)alloc((size_t)(N + 1) * 4);
    int*   cursor = (int*)alloc((size_t)(N + 1) * 4);
    int*   colidx = (int*)alloc((size_t)E * 4);
    int*   cdeg   = (int*)alloc((size_t)(NC + 1) * 4);
    int*   cptr   = (int*)alloc((size_t)(NC + 1) * 4);
    int*   ccur   = (int*)alloc((size_t)(NC + 1) * 4);
    int*   cidx   = (int*)alloc((size_t)N * 4);

    const int* src = ei;
    const int* dst = ei + E;

    hipMemsetAsync(deg, 0, (size_t)N * 4, stream);
    hipMemsetAsync(cdeg, 0, (size_t)NC * 4, stream);
    hipMemsetAsync(sumsq, 0, 512 * 4, stream);

    // edge CSR (keyed by dst, storing src)
    k_hist<<<(E + 255) / 256, 256, 0, stream>>>(dst, E, deg);
    k_scan<<<1, 1024, 0, stream>>>(deg, N, rowptr, cursor);
    k_scatter_edges<<<(E + 255) / 256, 256, 0, stream>>>(dst, src, E, cursor, colidx);

    // cluster CSR
    k_hist<<<(N + 255) / 256, 256, 0, stream>>>(cluster, N, cdeg);
    k_scan<<<1, 1024, 0, stream>>>(cdeg, NC, cptr, ccur);
    k_scatter_nodes<<<(N + 255) / 256, 256, 0, stream>>>(cluster, N, ccur, cidx);

    const int Mtiles = (N + 63) / 64;
    const int aggBlocks = (N * 64 + 255) / 256;

    // layer 0: c=64
    k_mlp1<64><<<Mtiles, 256, 0, stream>>>(x0, w1_[0], b1_[0], tbuf, N);
    k_mlp2<<<dim3(Mtiles, 1), 256, 0, stream>>>(tbuf, w2_[0], b2_[0], x1, N, 64, 128);
    k_agg<1><<<aggBlocks, 256, 0, stream>>>(x1, x1 + 64, rowptr, colidx, N, 128);

    // layer 1: c=128
    k_mlp1<128><<<Mtiles, 256, 0, stream>>>(x1, w1_[1], b1_[1], tbuf, N);
    k_mlp2<<<dim3(Mtiles, 2), 256, 0, stream>>>(tbuf, w2_[1], b2_[1], x2, N, 128, 256);
    k_agg<2><<<aggBlocks, 256, 0, stream>>>(x2, x2 + 128, rowptr, colidx, N, 256);

    // layer 2: c=256
    k_mlp1<256><<<Mtiles, 256, 0, stream>>>(x2, w1_[2], b1_[2], tbuf, N);
    k_mlp2<<<dim3(Mtiles, 4), 256, 0, stream>>>(tbuf, w2_[2], b2_[2], x3, N, 256, 512);
    k_agg<4><<<aggBlocks, 256, 0, stream>>>(x3, x3 + 256, rowptr, colidx, N, 512);

    // cluster max-pool + column norm
    k_pool<<<NC, 256, 0, stream>>>(x3, cptr, cidx, pooled);
    k_sumsq<<<128, 256, 0, stream>>>(pooled, sumsq, NC);
    k_scale<<<(out_size / 4 + 255) / 256, 256, 0, stream>>>(pooled, sumsq, out, out_size);
}